// Round 6
// baseline (232.195 us; speedup 1.0000x reference)
//
#include <hip/hip_runtime.h>
#include <hip/hip_bf16.h>
#include <stdint.h>

#define IN_F 1024
#define OUT_F 1024
#define NB 8
#define KDIM (IN_F + IN_F * NB)  /* 9216 */
#define NROWS 4096
#define SLICE_ELEMS (NROWS * OUT_F)
#define PREP_BLOCKS ((NROWS * IN_F) / 256)        /* 16384 */
#define WCONV_BLOCKS ((OUT_F * KDIM) / (4 * 256)) /* 9216  */

typedef __attribute__((ext_vector_type(8))) short bf16x8;
typedef __attribute__((ext_vector_type(4))) short bf16x4;
typedef __attribute__((ext_vector_type(4))) float f32x4;

// Closed-form uniform cubic B-spline (knots t_j = -2.2 + 0.4j; EPS=1e-8 shift is
// far below bf16 rounding). For x in [t_i,t_{i+1}): 4 nonzero cardinal cubics.
__device__ __forceinline__ void bspline8(float x, float b8[8]) {
  float u = (x + 2.2f) * 2.5f;  // (x - t0)/h
  bool in = (u >= 0.0f) && (u < 11.0f);
  float uc = fminf(fmaxf(u, 0.0f), 10.99f);
  int i = (int)uc;
  float f = uc - (float)i;
  float g = 1.0f - f;
  float f2 = f * f, f3 = f2 * f;
  const float s = 1.0f / 6.0f;
  float v0 = f3 * s;
  float v1 = (-3.0f * f3 + 3.0f * f2 + 3.0f * f + 1.0f) * s;
  float v2 = (3.0f * f3 - 6.0f * f2 + 4.0f) * s;
  float v3 = g * g * g * s;
#pragma unroll
  for (int j = 0; j < 8; ++j) {
    int d = i - j;
    float r = (d == 0) ? v0 : (d == 1) ? v1 : (d == 2) ? v2 : (d == 3) ? v3 : 0.0f;
    b8[j] = in ? r : 0.0f;
  }
}

// Fused prep (A build) + weight conversion, branch on blockIdx (block-uniform).
__global__ void prep_all_kernel(const float* __restrict__ x, const float* __restrict__ bw,
                                const float* __restrict__ sw, __hip_bfloat16* __restrict__ A,
                                __hip_bfloat16* __restrict__ W) {
  if (blockIdx.x < PREP_BLOCKS) {
    int idx = blockIdx.x * 256 + threadIdx.x;
    int n = idx >> 10;
    int i = idx & 1023;
    float xv = x[idx];
    float sl = xv / (1.0f + __expf(-xv));
    __hip_bfloat16* row = A + (size_t)n * KDIM;
    row[i] = __float2bfloat16(sl);
    float b8[8];
    bspline8(xv, b8);
    alignas(16) __hip_bfloat16 tmp[8];
#pragma unroll
    for (int c = 0; c < 8; ++c) tmp[c] = __float2bfloat16(b8[c]);
    *(bf16x8*)(row + IN_F + i * 8) = *(const bf16x8*)tmp;
  } else {
    int v = (blockIdx.x - PREP_BLOCKS) * 256 + threadIdx.x;
    int e = v * 4;
    int o = e / KDIM;
    int k = e - o * KDIM;
    float4 val = (k < IN_F) ? *(const float4*)(bw + o * IN_F + k)
                            : *(const float4*)(sw + (size_t)o * (IN_F * NB) + (k - IN_F));
    alignas(8) __hip_bfloat16 t[4];
    t[0] = __float2bfloat16(val.x);
    t[1] = __float2bfloat16(val.y);
    t[2] = __float2bfloat16(val.z);
    t[3] = __float2bfloat16(val.w);
    *(bf16x4*)(W + e) = *(const bf16x4*)t;
  }
}

// ---------------------------------------------------------------------------
// 256x256-tile, BK=64, 8-wave (2Mx4N), 4 phases per K-tile. R6 = R5's balanced
// schedule with the phi4 operand bug FIXED: R5's phi4 loaded next-tile b01 and
// then used b01 in the same phase's MFMA (C semantics -> MFMA consumed the NEW
// fragments -> wrong K-slice, absmax 5.78). Fix: reorder quadrants so phi4's
// MFMA is a03 x b23 -- disjoint from the b01 prefetch registers.
//   phi1: LOAD_A03(P) [8 rd] ; MFMA a03xb01  (b01 prefetched prev phi4)
//   phi2: LOAD_A47(P) [8 rd] ; MFMA a47xb01  (b01 last use)
//   phi3: LOAD_B23(P) [4 rd] + stage T2.A->P (A(P) reads retired phi2)
//         ; MFMA a47xb23
//   phi4: stage T2.B->P (b01(P) reads retired phi1, b23 phi3); vmcnt(8);
//         barrier; LOAD_B01(P^1) [4 rd, NOT an operand below]; MFMA a03xb23
// Read distribution {8,8,4,4} (R2 was {16,8,0,0}: LDS burst serialized against
// MFMA). Same barrier/lgkmcnt(0) discipline as R2 (best measured). vmcnt(8) =
// exactly tile t+2's 8 in-flight loads, drains t+1 before its slot is read.
// Pair-unrolled: all slot indices compile-time. No XCD swizzle (R4: not
// memory-bound). LDS fragment-ordered -> 0 bank conflicts. 128 KB LDS ->
// 1 block/CU, grid 16x4x4 = 256 = 1/CU.
// ---------------------------------------------------------------------------
__global__ __launch_bounds__(512, 2) void gemm8_kernel(const __hip_bfloat16* __restrict__ A,
                                                       const __hip_bfloat16* __restrict__ W,
                                                       float* __restrict__ dst,
                                                       const float* __restrict__ bias,
                                                       int kslice, int use_bias) {
  __shared__ __hip_bfloat16 lA[2][16384];
  __shared__ __hip_bfloat16 lB[2][16384];
  const int tid = threadIdx.x;
  const int wave = tid >> 6;
  const int lane = tid & 63;
  const int warp_m = wave >> 2;  // 0..1 -> 128-row half
  const int warp_n = wave & 3;   // 0..3 -> 64-col quarter
  const int bm = blockIdx.x * 256;
  const int bn = blockIdx.y * 256;
  const int z = blockIdx.z;

  float* __restrict__ d = dst + (size_t)z * SLICE_ELEMS;
  const int kbeg = z * kslice;
  const int NT = kslice >> 6;  // K-tiles of 64
  const int NIT = NT >> 1;     // pair-unrolled
  const int srow = lane & 15;
  const int skc = (lane >> 4) * 8;
  const int r = lane & 15;
  const int quad = lane >> 4;

  const __hip_bfloat16* rowA[2];
  const __hip_bfloat16* rowB[2];
  rowA[0] = A + (size_t)(bm + (0 * 8 + wave) * 16 + srow) * KDIM + kbeg + skc;
  rowA[1] = A + (size_t)(bm + (1 * 8 + wave) * 16 + srow) * KDIM + kbeg + skc;
  rowB[0] = W + (size_t)(bn + (0 * 8 + wave) * 16 + srow) * KDIM + kbeg + skc;
  rowB[1] = W + (size_t)(bn + (1 * 8 + wave) * 16 + srow) * KDIM + kbeg + skc;

  f32x4 acc[8][4];
#pragma unroll
  for (int a = 0; a < 8; ++a)
#pragma unroll
    for (int b = 0; b < 4; ++b) acc[a][b] = (f32x4){0.f, 0.f, 0.f, 0.f};

#define GLOAD(SRC, DST)                                                                      \
  __builtin_amdgcn_global_load_lds((const __attribute__((address_space(1))) void*)(SRC),     \
                                   (__attribute__((address_space(3))) void*)(DST), 16, 0, 0)

  // HID: 0=A-half0, 1=A-half1, 2=B-half0, 3=B-half1. SLOT explicit.
#define STAGE_HALF(TILE, HID, SLOT)                                              \
  do {                                                                           \
    const int tu_ = (TILE);                                                      \
    const int ts_ = tu_ < NT ? tu_ : NT - 1;                                     \
    if ((HID) < 2) {                                                             \
      const __hip_bfloat16* s_ = rowA[(HID)] + (size_t)ts_ * 64;                 \
      __hip_bfloat16* d_ = &lA[(SLOT)][(((HID) * 8 + wave) * 2 + 0) * 512];      \
      GLOAD(s_, d_);                                                             \
      GLOAD(s_ + 32, d_ + 512);                                                  \
    } else {                                                                     \
      const __hip_bfloat16* s_ = rowB[(HID) - 2] + (size_t)ts_ * 64;             \
      __hip_bfloat16* d_ = &lB[(SLOT)][((((HID) - 2) * 8 + wave) * 2 + 0) * 512];\
      GLOAD(s_, d_);                                                             \
      GLOAD(s_ + 32, d_ + 512);                                                  \
    }                                                                            \
  } while (0)

  bf16x8 a03[4][2], a47[4][2], b01[2][2], b23[2][2];

#define LOAD_A03(SLOT)                                                                      \
  do {                                                                                      \
    _Pragma("unroll") for (int t = 0; t < 4; ++t) {                                         \
      a03[t][0] = *(const bf16x8*)&lA[(SLOT)][((warp_m * 8 + t) * 2 + 0) * 512 + lane * 8]; \
      a03[t][1] = *(const bf16x8*)&lA[(SLOT)][((warp_m * 8 + t) * 2 + 1) * 512 + lane * 8]; \
    }                                                                                       \
  } while (0)
#define LOAD_A47(SLOT)                                                                          \
  do {                                                                                          \
    _Pragma("unroll") for (int t = 0; t < 4; ++t) {                                             \
      a47[t][0] = *(const bf16x8*)&lA[(SLOT)][((warp_m * 8 + 4 + t) * 2 + 0) * 512 + lane * 8]; \
      a47[t][1] = *(const bf16x8*)&lA[(SLOT)][((warp_m * 8 + 4 + t) * 2 + 1) * 512 + lane * 8]; \
    }                                                                                           \
  } while (0)
#define LOAD_B01(SLOT)                                                                      \
  do {                                                                                      \
    _Pragma("unroll") for (int u = 0; u < 2; ++u) {                                         \
      b01[u][0] = *(const bf16x8*)&lB[(SLOT)][((warp_n * 4 + u) * 2 + 0) * 512 + lane * 8]; \
      b01[u][1] = *(const bf16x8*)&lB[(SLOT)][((warp_n * 4 + u) * 2 + 1) * 512 + lane * 8]; \
    }                                                                                       \
  } while (0)
#define LOAD_B23(SLOT)                                                                          \
  do {                                                                                          \
    _Pragma("unroll") for (int u = 0; u < 2; ++u) {                                             \
      b23[u][0] =                                                                               \
          *(const bf16x8*)&lB[(SLOT)][((warp_n * 4 + 2 + u) * 2 + 0) * 512 + lane * 8];         \
      b23[u][1] =                                                                               \
          *(const bf16x8*)&lB[(SLOT)][((warp_n * 4 + 2 + u) * 2 + 1) * 512 + lane * 8];         \
    }                                                                                           \
  } while (0)

#define MFMA_QUAD(AF, BF, TM0, TN0)                                                          \
  do {                                                                                       \
    _Pragma("unroll") for (int tm = 0; tm < 4; ++tm)                                         \
    _Pragma("unroll") for (int tn = 0; tn < 2; ++tn)                                         \
    _Pragma("unroll") for (int s = 0; s < 2; ++s)                                            \
        acc[(TM0) + tm][(TN0) + tn] = __builtin_amdgcn_mfma_f32_16x16x32_bf16(               \
            AF[tm][s], BF[tn][s], acc[(TM0) + tm][(TN0) + tn], 0, 0, 0);                     \
  } while (0)

#define PIN() __builtin_amdgcn_sched_barrier(0)
#define PH_BAR_LGKM()                                        \
  do {                                                       \
    __builtin_amdgcn_s_barrier();                            \
    asm volatile("s_waitcnt lgkmcnt(0)" ::: "memory");       \
    PIN();                                                   \
  } while (0)
#define PH_END()                                             \
  do {                                                       \
    __builtin_amdgcn_s_setprio(0);                           \
    PIN();                                                   \
    __builtin_amdgcn_s_barrier();                            \
  } while (0)

  // One K-tile, slot P (compile-time 0/1). T2 = tile index to stage (t+2).
#define TILE_BODY(P, T2)                                         \
  do {                                                           \
    /* phi1: a03 x b01 (b01 prefetched at prev phi4) */          \
    LOAD_A03(P);                                                 \
    PH_BAR_LGKM();                                               \
    __builtin_amdgcn_s_setprio(1);                               \
    MFMA_QUAD(a03, b01, 0, 0);                                   \
    PH_END();                                                    \
    /* phi2: a47 x b01 (b01 last use) */                         \
    LOAD_A47(P);                                                 \
    PH_BAR_LGKM();                                               \
    __builtin_amdgcn_s_setprio(1);                               \
    MFMA_QUAD(a47, b01, 4, 0);                                   \
    PH_END();                                                    \
    /* phi3: a47 x b23; stage T2.A (A(P) reads retired phi2) */  \
    LOAD_B23(P);                                                 \
    STAGE_HALF(T2, 0, P);                                        \
    STAGE_HALF(T2, 1, P);                                        \
    PH_BAR_LGKM();                                               \
    __builtin_amdgcn_s_setprio(1);                               \
    MFMA_QUAD(a47, b23, 4, 2);                                   \
    PH_END();                                                    \
    /* phi4: stage T2.B (b01(P) reads retired phi1, b23 phi3); */\
    /* land tile t+1; prefetch next b01 (NOT an operand here); */\
    /* MFMA a03 x b23 */                                         \
    STAGE_HALF(T2, 2, P);                                        \
    STAGE_HALF(T2, 3, P);                                        \
    asm volatile("s_waitcnt vmcnt(8)" ::: "memory");             \
    PIN();                                                       \
    __builtin_amdgcn_s_barrier();                                \
    PIN();                                                       \
    LOAD_B01((P) ^ 1);                                           \
    __builtin_amdgcn_s_setprio(1);                               \
    MFMA_QUAD(a03, b23, 0, 2);                                   \
    PH_END();                                                    \
  } while (0)

  // ---- prologue: stage t0 (slot0) + t1 (slot1); land t0; pre-read b01(0) ----
  STAGE_HALF(0, 2, 0);
  STAGE_HALF(0, 3, 0);
  STAGE_HALF(0, 0, 0);
  STAGE_HALF(0, 1, 0);
  STAGE_HALF(1, 2, 1);
  STAGE_HALF(1, 3, 1);
  STAGE_HALF(1, 0, 1);
  STAGE_HALF(1, 1, 1);
  asm volatile("s_waitcnt vmcnt(8)" ::: "memory");
  PIN();
  __builtin_amdgcn_s_barrier();
  PIN();
  LOAD_B01(0);
  PIN();

  for (int i = 0; i < NIT; ++i) {
    TILE_BODY(0, 2 * i + 2);
    TILE_BODY(1, 2 * i + 3);
  }
  asm volatile("s_waitcnt vmcnt(0)" ::: "memory");

#undef TILE_BODY
#undef STAGE_HALF
#undef GLOAD
#undef LOAD_A03
#undef LOAD_A47
#undef LOAD_B01
#undef LOAD_B23
#undef MFMA_QUAD
#undef PH_BAR_LGKM
#undef PH_END
#undef PIN

  // C/D map: col=lane&15, row=quad*4+reg (m89-verified).
#pragma unroll
  for (int tm = 0; tm < 8; ++tm) {
#pragma unroll
    for (int tn = 0; tn < 4; ++tn) {
      const int col = bn + warp_n * 64 + tn * 16 + r;
      const float bv = use_bias ? bias[col] : 0.0f;
#pragma unroll
      for (int reg = 0; reg < 4; ++reg) {
        const int rowi = bm + warp_m * 128 + tm * 16 + quad * 4 + reg;
        d[(size_t)rowi * OUT_F + col] = acc[tm][tn][reg] + bv;
      }
    }
  }
}

// out = bias + sum_s partial[s], float4 per thread.
__global__ void reduce_kernel(const float* __restrict__ P, const float* __restrict__ bias,
                              float* __restrict__ out, int S) {
  int v = blockIdx.x * 256 + threadIdx.x;
  int e = v * 4;
  int o = e & (OUT_F - 1);
  float4 acc = *(const float4*)(bias + o);
  for (int s = 0; s < S; ++s) {
    float4 p = *(const float4*)(P + (size_t)s * SLICE_ELEMS + e);
    acc.x += p.x;
    acc.y += p.y;
    acc.z += p.z;
    acc.w += p.w;
  }
  *(float4*)(out + e) = acc;
}

// Emergency fallback if ws is too small for A+W (fp32, slow but correct).
__global__ void kan_fallback(const float* __restrict__ x, const float* __restrict__ bw,
                             const float* __restrict__ bb, const float* __restrict__ sw,
                             float* __restrict__ out) {
  __shared__ float act[KDIM];
  int n = blockIdx.x;
  for (int i = threadIdx.x; i < IN_F; i += 256) {
    float xv = x[(size_t)n * IN_F + i];
    act[i] = xv / (1.0f + __expf(-xv));
    float b8[8];
    bspline8(xv, b8);
#pragma unroll
    for (int c = 0; c < 8; ++c) act[IN_F + i * 8 + c] = b8[c];
  }
  __syncthreads();
  for (int o = threadIdx.x; o < OUT_F; o += 256) {
    float s = bb[o];
    const float* wbp = bw + (size_t)o * IN_F;
    for (int k = 0; k < IN_F; ++k) s += act[k] * wbp[k];
    const float* wsp = sw + (size_t)o * (IN_F * NB);
    for (int k = 0; k < IN_F * NB; ++k) s += act[IN_F + k] * wsp[k];
    out[(size_t)n * OUT_F + o] = s;
  }
}

extern "C" void kernel_launch(void* const* d_in, const int* in_sizes, int n_in, void* d_out,
                              int out_size, void* d_ws, size_t ws_size, hipStream_t stream) {
  const float* x = (const float*)d_in[0];
  const float* bw = (const float*)d_in[1];
  const float* bb = (const float*)d_in[2];
  const float* sw = (const float*)d_in[3];
  float* out = (float*)d_out;

  const size_t needA = (size_t)NROWS * KDIM * 2;  // 75.5 MB
  const size_t needW = (size_t)OUT_F * KDIM * 2;  // 18.9 MB
  const size_t sliceB = (size_t)SLICE_ELEMS * 4;  // 16.8 MB
  if (ws_size < needA + needW) {
    kan_fallback<<<NROWS, 256, 0, stream>>>(x, bw, bb, sw, out);
    return;
  }
  __hip_bfloat16* A = (__hip_bfloat16*)d_ws;
  __hip_bfloat16* W = (__hip_bfloat16*)((char*)d_ws + needA);
  float* P = (float*)((char*)d_ws + needA + needW);
  const size_t avail = ws_size - needA - needW;
  // S=4 -> 16x4x4 = 256 blocks = 1 block/CU (128 KB LDS). kslice=2304, NT=36.
  int S = (avail >= 4 * sliceB) ? 4 : (avail >= 2 * sliceB) ? 2 : 1;

  prep_all_kernel<<<PREP_BLOCKS + WCONV_BLOCKS, 256, 0, stream>>>(x, bw, sw, A, W);
  if (S == 1) {
    gemm8_kernel<<<dim3(NROWS / 256, OUT_F / 256, 1), 512, 0, stream>>>(A, W, out, bb, KDIM, 1);
  } else {
    gemm8_kernel<<<dim3(NROWS / 256, OUT_F / 256, S), 512, 0, stream>>>(A, W, P, bb, KDIM / S, 0);
    reduce_kernel<<<SLICE_ELEMS / (4 * 256), 256, 0, stream>>>(P, bb, out, S);
  }
}

// Round 7
// 224.939 us; speedup vs baseline: 1.0323x; 1.0323x over previous
//
#include <hip/hip_runtime.h>
#include <hip/hip_bf16.h>
#include <stdint.h>

#define IN_F 1024
#define OUT_F 1024
#define NB 8
#define KDIM (IN_F + IN_F * NB)  /* 9216 */
#define NROWS 4096
#define SLICE_ELEMS (NROWS * OUT_F)
#define PREP_BLOCKS ((NROWS * IN_F) / 256)        /* 16384 */
#define WCONV_BLOCKS ((OUT_F * KDIM) / (4 * 256)) /* 9216  */

typedef __attribute__((ext_vector_type(8))) short bf16x8;
typedef __attribute__((ext_vector_type(4))) short bf16x4;
typedef __attribute__((ext_vector_type(4))) float f32x4;

// Closed-form uniform cubic B-spline (knots t_j = -2.2 + 0.4j; EPS=1e-8 shift is
// far below bf16 rounding). For x in [t_i,t_{i+1}): 4 nonzero cardinal cubics.
__device__ __forceinline__ void bspline8(float x, float b8[8]) {
  float u = (x + 2.2f) * 2.5f;  // (x - t0)/h
  bool in = (u >= 0.0f) && (u < 11.0f);
  float uc = fminf(fmaxf(u, 0.0f), 10.99f);
  int i = (int)uc;
  float f = uc - (float)i;
  float g = 1.0f - f;
  float f2 = f * f, f3 = f2 * f;
  const float s = 1.0f / 6.0f;
  float v0 = f3 * s;
  float v1 = (-3.0f * f3 + 3.0f * f2 + 3.0f * f + 1.0f) * s;
  float v2 = (3.0f * f3 - 6.0f * f2 + 4.0f) * s;
  float v3 = g * g * g * s;
#pragma unroll
  for (int j = 0; j < 8; ++j) {
    int d = i - j;
    float r = (d == 0) ? v0 : (d == 1) ? v1 : (d == 2) ? v2 : (d == 3) ? v3 : 0.0f;
    b8[j] = in ? r : 0.0f;
  }
}

// Fused prep (A build) + weight conversion, branch on blockIdx (block-uniform).
__global__ void prep_all_kernel(const float* __restrict__ x, const float* __restrict__ bw,
                                const float* __restrict__ sw, __hip_bfloat16* __restrict__ A,
                                __hip_bfloat16* __restrict__ W) {
  if (blockIdx.x < PREP_BLOCKS) {
    int idx = blockIdx.x * 256 + threadIdx.x;
    int n = idx >> 10;
    int i = idx & 1023;
    float xv = x[idx];
    float sl = xv / (1.0f + __expf(-xv));
    __hip_bfloat16* row = A + (size_t)n * KDIM;
    row[i] = __float2bfloat16(sl);
    float b8[8];
    bspline8(xv, b8);
    alignas(16) __hip_bfloat16 tmp[8];
#pragma unroll
    for (int c = 0; c < 8; ++c) tmp[c] = __float2bfloat16(b8[c]);
    *(bf16x8*)(row + IN_F + i * 8) = *(const bf16x8*)tmp;
  } else {
    int v = (blockIdx.x - PREP_BLOCKS) * 256 + threadIdx.x;
    int e = v * 4;
    int o = e / KDIM;
    int k = e - o * KDIM;
    float4 val = (k < IN_F) ? *(const float4*)(bw + o * IN_F + k)
                            : *(const float4*)(sw + (size_t)o * (IN_F * NB) + (k - IN_F));
    alignas(8) __hip_bfloat16 t[4];
    t[0] = __float2bfloat16(val.x);
    t[1] = __float2bfloat16(val.y);
    t[2] = __float2bfloat16(val.z);
    t[3] = __float2bfloat16(val.w);
    *(bf16x4*)(W + e) = *(const bf16x4*)t;
  }
}

// ---------------------------------------------------------------------------
// 256x256-tile, BK=64, 8-wave (2Mx4N). R7: faithful m201 phase plan.
// Reads are consumed IN the phase that issues them; distribution {12,8,4,0}:
//   phi1: read a03(8)+b01(4); lgkmcnt(8) pre-drain; bar; lgkm0; MFMA q00
//   phi2: read a47(8);                              bar; lgkm0; MFMA q10
//   phi3: read b23(4);                              bar; lgkm0; MFMA q01
//   phi4: (0 reads)  vmcnt(4); bar;                            MFMA q11
// Why R2's {16,8,0,0} was 6667 cyc/tile: 128 reads/CU burst must drain before
// ANY wave's MFMA (barrier+lgkm0 lockstep) -> phases alternate LDS/MFMA pipes.
// Smaller same-phase bursts drain across waves: earlier-drained waves MFMA
// while LDS serves the rest -> per-phase cost ~ max(drain, MFMA).
// Stage ledger, 1 half (2 gloads) EVERY phase (uniform, m201-style):
//   phi1: (t+1).B0 -> slot P^1   [B(P^1) readers retired at (t-1).phi3]
//   phi2: (t+1).B1 -> slot P^1
//   phi3: (t+2).A0 -> slot P     [A(P) readers retired at phi2-end: a03 phi1,
//   phi4: (t+2).A1 -> slot P      a47 phi2, own-wave lgkm0 before each barrier]
// vmcnt(4) at phi4: outstanding = t+1.{A0,A1}(from t-1) + t+1.{B0,B1} +
// t+2.{A0,A1} = 12 loads; drains 8 oldest = ALL of t+1, one barrier before
// t+1's phi1 reads. Leaves t+2.A0,A1 = 4. Prologue stages t0 fully + t1.A0,A1
// then vmcnt(4) = steady state from iter 0. Tail stages clamp to NT-1
// (dead-but-safe rewrites, counts preserved). B-halves CANNOT be staged
// earlier than next-tile phi1: warp_n 0-1 waves read B-half0 in BOTH phi1
// (b01) and phi3 (b23) -> B retires only at phi3 (the R5/R6 ledger flaw).
// LDS fragment-ordered (prep pre-gathers) -> 0 bank conflicts. 128 KB LDS ->
// 1 block/CU, grid 16x4x4 = 256 = 1/CU. No XCD swizzle (R4: not mem-bound).
// ---------------------------------------------------------------------------
__global__ __launch_bounds__(512, 2) void gemm8_kernel(const __hip_bfloat16* __restrict__ A,
                                                       const __hip_bfloat16* __restrict__ W,
                                                       float* __restrict__ dst,
                                                       const float* __restrict__ bias,
                                                       int kslice, int use_bias) {
  __shared__ __hip_bfloat16 lA[2][16384];
  __shared__ __hip_bfloat16 lB[2][16384];
  const int tid = threadIdx.x;
  const int wave = tid >> 6;
  const int lane = tid & 63;
  const int warp_m = wave >> 2;  // 0..1 -> 128-row half
  const int warp_n = wave & 3;   // 0..3 -> 64-col quarter
  const int bm = blockIdx.x * 256;
  const int bn = blockIdx.y * 256;
  const int z = blockIdx.z;

  float* __restrict__ d = dst + (size_t)z * SLICE_ELEMS;
  const int kbeg = z * kslice;
  const int NT = kslice >> 6;  // K-tiles of 64 (even for all S)
  const int NIT = NT >> 1;     // pair-unrolled
  const int srow = lane & 15;
  const int skc = (lane >> 4) * 8;
  const int r = lane & 15;
  const int quad = lane >> 4;

  const __hip_bfloat16* rowA[2];
  const __hip_bfloat16* rowB[2];
  rowA[0] = A + (size_t)(bm + (0 * 8 + wave) * 16 + srow) * KDIM + kbeg + skc;
  rowA[1] = A + (size_t)(bm + (1 * 8 + wave) * 16 + srow) * KDIM + kbeg + skc;
  rowB[0] = W + (size_t)(bn + (0 * 8 + wave) * 16 + srow) * KDIM + kbeg + skc;
  rowB[1] = W + (size_t)(bn + (1 * 8 + wave) * 16 + srow) * KDIM + kbeg + skc;

  f32x4 acc[8][4];
#pragma unroll
  for (int a = 0; a < 8; ++a)
#pragma unroll
    for (int b = 0; b < 4; ++b) acc[a][b] = (f32x4){0.f, 0.f, 0.f, 0.f};

#define GLOAD(SRC, DST)                                                                      \
  __builtin_amdgcn_global_load_lds((const __attribute__((address_space(1))) void*)(SRC),     \
                                   (__attribute__((address_space(3))) void*)(DST), 16, 0, 0)

  // HID: 0=A-half0, 1=A-half1, 2=B-half0, 3=B-half1. SLOT explicit.
#define STAGE_HALF(TILE, HID, SLOT)                                              \
  do {                                                                           \
    const int tu_ = (TILE);                                                      \
    const int ts_ = tu_ < NT ? tu_ : NT - 1;                                     \
    if ((HID) < 2) {                                                             \
      const __hip_bfloat16* s_ = rowA[(HID)] + (size_t)ts_ * 64;                 \
      __hip_bfloat16* d_ = &lA[(SLOT)][(((HID) * 8 + wave) * 2 + 0) * 512];      \
      GLOAD(s_, d_);                                                             \
      GLOAD(s_ + 32, d_ + 512);                                                  \
    } else {                                                                     \
      const __hip_bfloat16* s_ = rowB[(HID) - 2] + (size_t)ts_ * 64;             \
      __hip_bfloat16* d_ = &lB[(SLOT)][((((HID) - 2) * 8 + wave) * 2 + 0) * 512];\
      GLOAD(s_, d_);                                                             \
      GLOAD(s_ + 32, d_ + 512);                                                  \
    }                                                                            \
  } while (0)

  bf16x8 a03[4][2], a47[4][2], b01[2][2], b23[2][2];

#define LOAD_A03(SLOT)                                                                      \
  do {                                                                                      \
    _Pragma("unroll") for (int t = 0; t < 4; ++t) {                                         \
      a03[t][0] = *(const bf16x8*)&lA[(SLOT)][((warp_m * 8 + t) * 2 + 0) * 512 + lane * 8]; \
      a03[t][1] = *(const bf16x8*)&lA[(SLOT)][((warp_m * 8 + t) * 2 + 1) * 512 + lane * 8]; \
    }                                                                                       \
  } while (0)
#define LOAD_A47(SLOT)                                                                          \
  do {                                                                                          \
    _Pragma("unroll") for (int t = 0; t < 4; ++t) {                                             \
      a47[t][0] = *(const bf16x8*)&lA[(SLOT)][((warp_m * 8 + 4 + t) * 2 + 0) * 512 + lane * 8]; \
      a47[t][1] = *(const bf16x8*)&lA[(SLOT)][((warp_m * 8 + 4 + t) * 2 + 1) * 512 + lane * 8]; \
    }                                                                                           \
  } while (0)
#define LOAD_B01(SLOT)                                                                      \
  do {                                                                                      \
    _Pragma("unroll") for (int u = 0; u < 2; ++u) {                                         \
      b01[u][0] = *(const bf16x8*)&lB[(SLOT)][((warp_n * 4 + u) * 2 + 0) * 512 + lane * 8]; \
      b01[u][1] = *(const bf16x8*)&lB[(SLOT)][((warp_n * 4 + u) * 2 + 1) * 512 + lane * 8]; \
    }                                                                                       \
  } while (0)
#define LOAD_B23(SLOT)                                                                          \
  do {                                                                                          \
    _Pragma("unroll") for (int u = 0; u < 2; ++u) {                                             \
      b23[u][0] =                                                                               \
          *(const bf16x8*)&lB[(SLOT)][((warp_n * 4 + 2 + u) * 2 + 0) * 512 + lane * 8];         \
      b23[u][1] =                                                                               \
          *(const bf16x8*)&lB[(SLOT)][((warp_n * 4 + 2 + u) * 2 + 1) * 512 + lane * 8];         \
    }                                                                                           \
  } while (0)

#define MFMA_QUAD(AF, BF, TM0, TN0)                                                          \
  do {                                                                                       \
    _Pragma("unroll") for (int tm = 0; tm < 4; ++tm)                                         \
    _Pragma("unroll") for (int tn = 0; tn < 2; ++tn)                                         \
    _Pragma("unroll") for (int s = 0; s < 2; ++s)                                            \
        acc[(TM0) + tm][(TN0) + tn] = __builtin_amdgcn_mfma_f32_16x16x32_bf16(               \
            AF[tm][s], BF[tn][s], acc[(TM0) + tm][(TN0) + tn], 0, 0, 0);                     \
  } while (0)

#define PIN() __builtin_amdgcn_sched_barrier(0)
#define PH_BAR_LGKM()                                        \
  do {                                                       \
    __builtin_amdgcn_s_barrier();                            \
    asm volatile("s_waitcnt lgkmcnt(0)" ::: "memory");       \
    PIN();                                                   \
  } while (0)
#define PH_END()                                             \
  do {                                                       \
    __builtin_amdgcn_s_setprio(0);                           \
    PIN();                                                   \
    __builtin_amdgcn_s_barrier();                            \
  } while (0)

  // One K-tile, slot P (compile-time 0/1), tile index T (for stage targets).
#define TILE_BODY(P, T)                                          \
  do {                                                           \
    /* phi1: stage (T+1).B0->P^1; read a03+b01; MFMA q00 */      \
    STAGE_HALF((T) + 1, 2, (P) ^ 1);                             \
    LOAD_A03(P);                                                 \
    LOAD_B01(P);                                                 \
    asm volatile("s_waitcnt lgkmcnt(8)" ::: "memory");           \
    PIN();                                                       \
    PH_BAR_LGKM();                                               \
    __builtin_amdgcn_s_setprio(1);                               \
    MFMA_QUAD(a03, b01, 0, 0);                                   \
    PH_END();                                                    \
    /* phi2: stage (T+1).B1->P^1; read a47; MFMA q10 */          \
    STAGE_HALF((T) + 1, 3, (P) ^ 1);                             \
    LOAD_A47(P);                                                 \
    PH_BAR_LGKM();                                               \
    __builtin_amdgcn_s_setprio(1);                               \
    MFMA_QUAD(a47, b01, 4, 0);                                   \
    PH_END();                                                    \
    /* phi3: stage (T+2).A0->P (A(P) readers retired phi2-end); */\
    /* read b23; MFMA q01 */                                     \
    STAGE_HALF((T) + 2, 0, P);                                   \
    LOAD_B23(P);                                                 \
    PH_BAR_LGKM();                                               \
    __builtin_amdgcn_s_setprio(1);                               \
    MFMA_QUAD(a03, b23, 0, 2);                                   \
    PH_END();                                                    \
    /* phi4: stage (T+2).A1->P; vmcnt(4) lands ALL of tile T+1;  */\
    /* barrier; MFMA q11 (operands long retired, no lgkm wait) */\
    STAGE_HALF((T) + 2, 1, P);                                   \
    asm volatile("s_waitcnt vmcnt(4)" ::: "memory");             \
    PIN();                                                       \
    __builtin_amdgcn_s_barrier();                                \
    PIN();                                                       \
    __builtin_amdgcn_s_setprio(1);                               \
    MFMA_QUAD(a47, b23, 4, 2);                                   \
    PH_END();                                                    \
  } while (0)

  // ---- prologue: t0 fully -> slot0; t1.A0,A1 -> slot1; land t0 ----
  STAGE_HALF(0, 0, 0);
  STAGE_HALF(0, 1, 0);
  STAGE_HALF(0, 2, 0);
  STAGE_HALF(0, 3, 0);
  STAGE_HALF(1, 0, 1);
  STAGE_HALF(1, 1, 1);
  asm volatile("s_waitcnt vmcnt(4)" ::: "memory");
  PIN();
  __builtin_amdgcn_s_barrier();

  for (int i = 0; i < NIT; ++i) {
    TILE_BODY(0, 2 * i);
    TILE_BODY(1, 2 * i + 1);
  }
  asm volatile("s_waitcnt vmcnt(0)" ::: "memory");

#undef TILE_BODY
#undef STAGE_HALF
#undef GLOAD
#undef LOAD_A03
#undef LOAD_A47
#undef LOAD_B01
#undef LOAD_B23
#undef MFMA_QUAD
#undef PH_BAR_LGKM
#undef PH_END
#undef PIN

  // C/D map: col=lane&15, row=quad*4+reg (m89-verified).
#pragma unroll
  for (int tm = 0; tm < 8; ++tm) {
#pragma unroll
    for (int tn = 0; tn < 4; ++tn) {
      const int col = bn + warp_n * 64 + tn * 16 + r;
      const float bv = use_bias ? bias[col] : 0.0f;
#pragma unroll
      for (int reg = 0; reg < 4; ++reg) {
        const int rowi = bm + warp_m * 128 + tm * 16 + quad * 4 + reg;
        d[(size_t)rowi * OUT_F + col] = acc[tm][tn][reg] + bv;
      }
    }
  }
}

// out = bias + sum_s partial[s], float4 per thread.
__global__ void reduce_kernel(const float* __restrict__ P, const float* __restrict__ bias,
                              float* __restrict__ out, int S) {
  int v = blockIdx.x * 256 + threadIdx.x;
  int e = v * 4;
  int o = e & (OUT_F - 1);
  float4 acc = *(const float4*)(bias + o);
  for (int s = 0; s < S; ++s) {
    float4 p = *(const float4*)(P + (size_t)s * SLICE_ELEMS + e);
    acc.x += p.x;
    acc.y += p.y;
    acc.z += p.z;
    acc.w += p.w;
  }
  *(float4*)(out + e) = acc;
}

// Emergency fallback if ws is too small for A+W (fp32, slow but correct).
__global__ void kan_fallback(const float* __restrict__ x, const float* __restrict__ bw,
                             const float* __restrict__ bb, const float* __restrict__ sw,
                             float* __restrict__ out) {
  __shared__ float act[KDIM];
  int n = blockIdx.x;
  for (int i = threadIdx.x; i < IN_F; i += 256) {
    float xv = x[(size_t)n * IN_F + i];
    act[i] = xv / (1.0f + __expf(-xv));
    float b8[8];
    bspline8(xv, b8);
#pragma unroll
    for (int c = 0; c < 8; ++c) act[IN_F + i * 8 + c] = b8[c];
  }
  __syncthreads();
  for (int o = threadIdx.x; o < OUT_F; o += 256) {
    float s = bb[o];
    const float* wbp = bw + (size_t)o * IN_F;
    for (int k = 0; k < IN_F; ++k) s += act[k] * wbp[k];
    const float* wsp = sw + (size_t)o * (IN_F * NB);
    for (int k = 0; k < IN_F * NB; ++k) s += act[IN_F + k] * wsp[k];
    out[(size_t)n * OUT_F + o] = s;
  }
}

extern "C" void kernel_launch(void* const* d_in, const int* in_sizes, int n_in, void* d_out,
                              int out_size, void* d_ws, size_t ws_size, hipStream_t stream) {
  const float* x = (const float*)d_in[0];
  const float* bw = (const float*)d_in[1];
  const float* bb = (const float*)d_in[2];
  const float* sw = (const float*)d_in[3];
  float* out = (float*)d_out;

  const size_t needA = (size_t)NROWS * KDIM * 2;  // 75.5 MB
  const size_t needW = (size_t)OUT_F * KDIM * 2;  // 18.9 MB
  const size_t sliceB = (size_t)SLICE_ELEMS * 4;  // 16.8 MB
  if (ws_size < needA + needW) {
    kan_fallback<<<NROWS, 256, 0, stream>>>(x, bw, bb, sw, out);
    return;
  }
  __hip_bfloat16* A = (__hip_bfloat16*)d_ws;
  __hip_bfloat16* W = (__hip_bfloat16*)((char*)d_ws + needA);
  float* P = (float*)((char*)d_ws + needA + needW);
  const size_t avail = ws_size - needA - needW;
  // S=4 -> 16x4x4 = 256 blocks = 1 block/CU (128 KB LDS). kslice=2304, NT=36.
  int S = (avail >= 4 * sliceB) ? 4 : (avail >= 2 * sliceB) ? 2 : 1;

  prep_all_kernel<<<PREP_BLOCKS + WCONV_BLOCKS, 256, 0, stream>>>(x, bw, sw, A, W);
  if (S == 1) {
    gemm8_kernel<<<dim3(NROWS / 256, OUT_F / 256, 1), 512, 0, stream>>>(A, W, out, bb, KDIM, 1);
  } else {
    gemm8_kernel<<<dim3(NROWS / 256, OUT_F / 256, S), 512, 0, stream>>>(A, W, P, bb, KDIM / S, 0);
    reduce_kernel<<<SLICE_ELEMS / (4 * 256), 256, 0, stream>>>(P, bb, out, S);
  }
}